// Round 1
// baseline (202.125 us; speedup 1.0000x reference)
//
#include <hip/hip_runtime.h>
#include <hip/hip_bf16.h>

typedef __attribute__((ext_vector_type(8))) short short8;
typedef __attribute__((ext_vector_type(4))) float f32x4;

#define D_MODEL 512
#define BN 128
#define BK 32
#define NSTEPS (D_MODEL / BK)   // 16

// round-to-nearest-even f32 -> bf16 (finite inputs only)
__device__ inline short f2bf(float f) {
    unsigned u = __builtin_bit_cast(unsigned, f);
    unsigned r = (u + 0x7fffu + ((u >> 16) & 1u)) >> 16;
    return (short)r;
}

// Kernel 1: cond[b][k] = ent[s_ent[b]][k] + rel[relation[b]][k]  (bf16 -> ws)
//           a2[b] = ||cond_fp32||^2
__global__ void prep_kernel(const int* __restrict__ s_ent, const int* __restrict__ rel,
                            const float* __restrict__ ent, const float* __restrict__ relemb,
                            short* __restrict__ condb, float* __restrict__ a2) {
    const int b = blockIdx.x;
    const int t = threadIdx.x;                       // 128 threads, 4 floats each
    const float4 v = *(const float4*)(ent + (size_t)s_ent[b] * D_MODEL + t * 4);
    const float4 w = *(const float4*)(relemb + (size_t)rel[b] * D_MODEL + t * 4);
    float c0 = v.x + w.x, c1 = v.y + w.y, c2 = v.z + w.z, c3 = v.w + w.w;
    float sq = c0 * c0 + c1 * c1 + c2 * c2 + c3 * c3;

    short4 s;
    s.x = f2bf(c0); s.y = f2bf(c1); s.z = f2bf(c2); s.w = f2bf(c3);
    *(short4*)(condb + (size_t)b * D_MODEL + t * 4) = s;

    // reduce sq across 128 threads (2 waves)
    #pragma unroll
    for (int off = 1; off < 64; off <<= 1) sq += __shfl_xor(sq, off);
    __shared__ float red[2];
    if ((t & 63) == 0) red[t >> 6] = sq;
    __syncthreads();
    if (t == 0) a2[b] = red[0] + red[1];
}

// Kernel 2: scores[m][n] = -sqrt(max(a2[m] - 2*(cond_m . ent_n) + b2[n], 1e-12))
// BM=256 (all queries), BN=128 entities/block, BK=32, 512 threads = 8 waves (4M x 2N).
__global__ __launch_bounds__(512, 4)
void score_kernel(const float* __restrict__ ent, const short* __restrict__ condb,
                  const float* __restrict__ a2, float* __restrict__ out, const int n_ent) {
    // B tile LDS: [2 buf][128 rows][40 shorts]  (32 data + 8 pad -> 80B stride, 2-way banks = free)
    __shared__ __align__(16) short Bl[2][BN * 40];
    __shared__ float b2s[BN];

    const int tid  = threadIdx.x;
    const int lane = tid & 63;
    const int w    = tid >> 6;
    const int wm   = w >> 1;         // 0..3  (64 rows of M each)
    const int wn   = w & 1;          // 0..1  (64 cols of N each)
    const int lrow = lane & 15;
    const int lk   = (lane >> 4) * 8;
    const int nbase = blockIdx.x * BN;

    // staging: thread -> (row, k-slot). 128 rows x 4 slots of 8 floats.
    const int sr = tid >> 2;
    const int sk = (tid & 3) * 8;
    const bool rvalid = (nbase + sr) < n_ent;
    const float* gsrc = ent + (size_t)(nbase + sr) * D_MODEL + sk;

    f32x4 acc[4][4] = {};
    float sq = 0.f;

    float4 p0 = {0.f, 0.f, 0.f, 0.f}, p1 = {0.f, 0.f, 0.f, 0.f};
    if (rvalid) { p0 = *(const float4*)(gsrc); p1 = *(const float4*)(gsrc + 4); }

    #pragma unroll 2
    for (int t = 0; t < NSTEPS; ++t) {
        // convert + write tile t into buf[t&1]; accumulate ||b||^2 in fp32
        sq += p0.x * p0.x + p0.y * p0.y + p0.z * p0.z + p0.w * p0.w
            + p1.x * p1.x + p1.y * p1.y + p1.z * p1.z + p1.w * p1.w;
        short8 bs;
        bs[0] = f2bf(p0.x); bs[1] = f2bf(p0.y); bs[2] = f2bf(p0.z); bs[3] = f2bf(p0.w);
        bs[4] = f2bf(p1.x); bs[5] = f2bf(p1.y); bs[6] = f2bf(p1.z); bs[7] = f2bf(p1.w);
        *(short8*)(&Bl[t & 1][sr * 40 + sk]) = bs;

        // prefetch tile t+1 (lands during barrier + compute)
        if (t < NSTEPS - 1 && rvalid) {
            p0 = *(const float4*)(gsrc + (t + 1) * BK);
            p1 = *(const float4*)(gsrc + (t + 1) * BK + 4);
        }

        __syncthreads();   // buf[t&1] ready for all waves

        // A fragments straight from global (cond is 256KB, L2-resident)
        const short* abase = condb + (size_t)(wm * 64 + lrow) * D_MODEL + t * BK + lk;
        short8 af[4];
        #pragma unroll
        for (int fm = 0; fm < 4; ++fm) af[fm] = *(const short8*)(abase + fm * 16 * D_MODEL);

        #pragma unroll
        for (int fn = 0; fn < 4; ++fn) {
            short8 bfv = *(const short8*)(&Bl[t & 1][(wn * 64 + fn * 16 + lrow) * 40 + lk]);
            #pragma unroll
            for (int fm = 0; fm < 4; ++fm)
                acc[fm][fn] = __builtin_amdgcn_mfma_f32_16x16x32_bf16(af[fm], bfv, acc[fm][fn], 0, 0, 0);
        }
        // NOTE: next iter writes buf[(t+1)&1] (other buffer) before its barrier -> safe
    }

    // finish b2: reduce 4 threads per row (lanes t^1, t^2 within wave)
    sq += __shfl_xor(sq, 1);
    sq += __shfl_xor(sq, 2);
    if ((tid & 3) == 0) b2s[sr] = sq;
    __syncthreads();

    // epilogue: d2 = a2[m] - 2*ab + b2[n]; score = -sqrt(max(d2, 1e-12))
    #pragma unroll
    for (int fm = 0; fm < 4; ++fm) {
        const int m = wm * 64 + fm * 16 + (lane >> 4) * 4;
        const f32x4 a2v = *(const f32x4*)(a2 + m);
        #pragma unroll
        for (int fn = 0; fn < 4; ++fn) {
            const int nl = wn * 64 + fn * 16 + lrow;
            const int ng = nbase + nl;
            if (ng < n_ent) {
                const float b2v = b2s[nl];
                #pragma unroll
                for (int r = 0; r < 4; ++r) {
                    float d2 = a2v[r] - 2.f * acc[fm][fn][r] + b2v;
                    out[(size_t)(m + r) * n_ent + ng] = -sqrtf(fmaxf(d2, 1e-12f));
                }
            }
        }
    }
}

extern "C" void kernel_launch(void* const* d_in, const int* in_sizes, int n_in,
                              void* d_out, int out_size, void* d_ws, size_t ws_size,
                              hipStream_t stream) {
    const int*   s_ent  = (const int*)d_in[0];
    const int*   rel    = (const int*)d_in[1];
    // d_in[2] = o_ent, d_in[3] = time : unused by reference forward
    const float* ent    = (const float*)d_in[4];
    const float* relemb = (const float*)d_in[5];
    float* out = (float*)d_out;

    const int bs    = in_sizes[0];              // 256
    const int n_ent = in_sizes[4] / D_MODEL;    // 200000

    short* condb = (short*)d_ws;                               // bs*512 bf16 = 256KB
    float* a2    = (float*)((char*)d_ws + (size_t)bs * D_MODEL * 2);

    prep_kernel<<<bs, 128, 0, stream>>>(s_ent, rel, ent, relemb, condb, a2);

    const int ntiles = (n_ent + BN - 1) / BN;   // 1563
    score_kernel<<<ntiles, 512, 0, stream>>>(ent, condb, a2, out, n_ent);
}

// Round 2
// 164.606 us; speedup vs baseline: 1.2279x; 1.2279x over previous
//
#include <hip/hip_runtime.h>
#include <hip/hip_bf16.h>

typedef __attribute__((ext_vector_type(8))) short short8;
typedef __attribute__((ext_vector_type(4))) float f32x4;

#define D_MODEL 512
#define BN 128
#define NT 16
#define A_TILE 16384   // 256 rows x 64B (bf16, k-slice of 32)
#define B_TILE 16384   // 128 rows x 128B (fp32, k-slice of 32)

__device__ __forceinline__ void gload16(const void* gptr, void* lptr) {
    typedef const __attribute__((address_space(1))) unsigned GT;
    typedef __attribute__((address_space(3))) unsigned LT;
    __builtin_amdgcn_global_load_lds((GT*)gptr, (LT*)lptr, 16, 0, 0);
}

// round-to-nearest-even f32 -> bf16 (finite inputs only)
__device__ __forceinline__ short f2bf(float f) {
    unsigned u = __builtin_bit_cast(unsigned, f);
    unsigned r = (u + 0x7fffu + ((u >> 16) & 1u)) >> 16;
    return (short)r;
}

// Kernel 1: cond[b][k] = ent[s_ent[b]][k] + rel[relation[b]][k]  (bf16 -> ws)
//           a2[b] = ||cond_fp32||^2
__global__ void prep_kernel(const int* __restrict__ s_ent, const int* __restrict__ rel,
                            const float* __restrict__ ent, const float* __restrict__ relemb,
                            short* __restrict__ condb, float* __restrict__ a2) {
    const int b = blockIdx.x;
    const int t = threadIdx.x;                       // 128 threads, 4 floats each
    const float4 v = *(const float4*)(ent + (size_t)s_ent[b] * D_MODEL + t * 4);
    const float4 w = *(const float4*)(relemb + (size_t)rel[b] * D_MODEL + t * 4);
    float c0 = v.x + w.x, c1 = v.y + w.y, c2 = v.z + w.z, c3 = v.w + w.w;
    float sq = c0 * c0 + c1 * c1 + c2 * c2 + c3 * c3;

    short4 s;
    s.x = f2bf(c0); s.y = f2bf(c1); s.z = f2bf(c2); s.w = f2bf(c3);
    *(short4*)(condb + (size_t)b * D_MODEL + t * 4) = s;

    #pragma unroll
    for (int off = 1; off < 64; off <<= 1) sq += __shfl_xor(sq, off);
    __shared__ float red[2];
    if ((t & 63) == 0) red[t >> 6] = sq;
    __syncthreads();
    if (t == 0) a2[b] = red[0] + red[1];
}

// Kernel 2: scores[m][n] = -sqrt(max(a2[m] - 2*(cond_m . ent_n) + b2[n], 1e-12))
// BM=256 (all queries, ent streamed exactly once), BN=128, BK=32, 512 thr = 8 waves (4M x 2N).
// A (bf16) ring-2 + B (fp32) ring-3 staged via global_load_lds; counted vmcnt, raw barriers.
__global__ __launch_bounds__(512, 4)
void score_kernel(const float* __restrict__ ent, const short* __restrict__ condb,
                  const float* __restrict__ a2, float* __restrict__ out, const int n_ent) {
    __shared__ __align__(16) unsigned char lds[2 * A_TILE + 3 * B_TILE];  // 80 KiB
    unsigned char* Al = lds;
    unsigned char* Bl = lds + 2 * A_TILE;

    const int tid  = threadIdx.x;
    const int lane = tid & 63;
    const int w    = tid >> 6, wm = w >> 1, wn = w & 1;
    const int lrow = lane & 15, g4 = lane >> 4;
    const int nbase = blockIdx.x * BN;

    // staging: phys LDS byte p = tid*16 (+8192 for second issue); LDS stays linear,
    // the XOR-swizzle is applied on the GLOBAL source column (rule #21).
    const int p0 = tid * 16, p1 = p0 + 8192;
    const int ar0 = p0 >> 6, ar1 = p1 >> 6;                 // A rows 0..127 / 128..255
    const char* gA0 = (const char*)condb + ar0 * 1024 + ((p0 & 63) ^ ((ar0 & 3) << 4));
    const char* gA1 = (const char*)condb + ar1 * 1024 + ((p1 & 63) ^ ((ar1 & 3) << 4));
    const int br0 = p0 >> 7, br1 = p1 >> 7;                 // B rows 0..63 / 64..127
    const long long gr0 = min(nbase + br0, n_ent - 1);      // clamp tail block
    const long long gr1 = min(nbase + br1, n_ent - 1);
    const char* gB0 = (const char*)ent + gr0 * 2048 + ((p0 & 127) ^ ((br0 & 7) << 4));
    const char* gB1 = (const char*)ent + gr1 * 2048 + ((p1 & 127) ^ ((br1 & 7) << 4));

    // per-lane LDS read offsets (swizzled, step-invariant)
    int aoff[4], boff0[4], boff1[4];
    #pragma unroll
    for (int f = 0; f < 4; ++f) {
        const int ra = wm * 64 + f * 16 + lrow;
        aoff[f] = ra * 64 + ((g4 * 16) ^ ((ra & 3) << 4));
        const int rb = wn * 64 + f * 16 + lrow;
        const int sw = (rb & 7) << 4;
        boff0[f] = rb * 128 + ((g4 * 32) ^ sw);
        boff1[f] = rb * 128 + ((g4 * 32 + 16) ^ sw);
    }

    f32x4 acc[4][4] = {};
    float sq[4] = {0.f, 0.f, 0.f, 0.f};

    // prologue: issue A(0), B(0), B(1)   -> outstanding [A0,A0,B0,B0,B1,B1]
    gload16(gA0, Al + p0);
    gload16(gA1, Al + p1);
    gload16(gB0, Bl + p0);
    gload16(gB1, Bl + p1);
    gload16(gB0 + 128, Bl + B_TILE + p0);
    gload16(gB1 + 128, Bl + B_TILE + p1);

    for (int t = 0; t < NT; ++t) {
        // steady state entering iter t: [B(t)x2, A(t)x2, B(t+1)x2] -> wait(2) drains B(t),A(t)
        if (t == NT - 1) { asm volatile("s_waitcnt vmcnt(0)" ::: "memory"); }
        else             { asm volatile("s_waitcnt vmcnt(2)" ::: "memory"); }
        __builtin_amdgcn_s_barrier();

        // issue next tiles (A first, then B: keeps B(t+1) outstanding across the wait)
        if (t + 1 < NT) {
            unsigned char* ad = Al + ((t + 1) & 1) * A_TILE;
            gload16(gA0 + (t + 1) * 64, ad + p0);
            gload16(gA1 + (t + 1) * 64, ad + p1);
        }
        if (t + 2 < NT) {
            unsigned char* bd = Bl + ((t + 2) % 3) * B_TILE;
            gload16(gB0 + (t + 2) * 128, bd + p0);
            gload16(gB1 + (t + 2) * 128, bd + p1);
        }

        const unsigned char* ab = Al + (t & 1) * A_TILE;
        const unsigned char* bb = Bl + (t % 3) * B_TILE;

        short8 af[4];
        #pragma unroll
        for (int fm = 0; fm < 4; ++fm) af[fm] = *(const short8*)(ab + aoff[fm]);

        #pragma unroll
        for (int fn = 0; fn < 4; ++fn) {
            const f32x4 v0 = *(const f32x4*)(bb + boff0[fn]);
            const f32x4 v1 = *(const f32x4*)(bb + boff1[fn]);
            if (wm == 0)  // b2 accumulated free from the staged fp32 values (2 waves)
                sq[fn] += v0[0]*v0[0] + v0[1]*v0[1] + v0[2]*v0[2] + v0[3]*v0[3]
                        + v1[0]*v1[0] + v1[1]*v1[1] + v1[2]*v1[2] + v1[3]*v1[3];
            union { __hip_bfloat162 h[4]; short8 s; } cv;
            cv.h[0] = __float22bfloat162_rn(make_float2(v0[0], v0[1]));
            cv.h[1] = __float22bfloat162_rn(make_float2(v0[2], v0[3]));
            cv.h[2] = __float22bfloat162_rn(make_float2(v1[0], v1[1]));
            cv.h[3] = __float22bfloat162_rn(make_float2(v1[2], v1[3]));
            #pragma unroll
            for (int fm = 0; fm < 4; ++fm)
                acc[fm][fn] = __builtin_amdgcn_mfma_f32_16x16x32_bf16(af[fm], cv.s, acc[fm][fn], 0, 0, 0);
        }
    }

    // b2 -> lds[0..512) (A-buf0 region; no live reads overlap it after final barrier)
    float* b2s = (float*)lds;
    if (wm == 0) {
        #pragma unroll
        for (int fn = 0; fn < 4; ++fn) {
            sq[fn] += __shfl_xor(sq[fn], 16);   // sum the 4 k-groups
            sq[fn] += __shfl_xor(sq[fn], 32);
        }
        if (lane < 16) {
            #pragma unroll
            for (int fn = 0; fn < 4; ++fn) b2s[wn * 64 + fn * 16 + lane] = sq[fn];
        }
    }
    __syncthreads();

    #pragma unroll
    for (int fm = 0; fm < 4; ++fm) {
        const int m0 = wm * 64 + fm * 16 + g4 * 4;
        const f32x4 a2v = *(const f32x4*)(a2 + m0);
        #pragma unroll
        for (int fn = 0; fn < 4; ++fn) {
            const int nl = wn * 64 + fn * 16 + lrow;
            const int ng = nbase + nl;
            if (ng < n_ent) {
                const float b2v = b2s[nl];
                #pragma unroll
                for (int r = 0; r < 4; ++r) {
                    float d2 = a2v[r] - 2.f * acc[fm][fn][r] + b2v;
                    out[(size_t)(m0 + r) * n_ent + ng] = -sqrtf(fmaxf(d2, 1e-12f));
                }
            }
        }
    }
}

extern "C" void kernel_launch(void* const* d_in, const int* in_sizes, int n_in,
                              void* d_out, int out_size, void* d_ws, size_t ws_size,
                              hipStream_t stream) {
    const int*   s_ent  = (const int*)d_in[0];
    const int*   rel    = (const int*)d_in[1];
    // d_in[2] = o_ent, d_in[3] = time : unused by reference forward
    const float* ent    = (const float*)d_in[4];
    const float* relemb = (const float*)d_in[5];
    float* out = (float*)d_out;

    const int bs    = in_sizes[0];              // 256
    const int n_ent = in_sizes[4] / D_MODEL;    // 200000

    short* condb = (short*)d_ws;                               // bs*512 bf16 = 256KB
    float* a2    = (float*)((char*)d_ws + (size_t)bs * D_MODEL * 2);

    prep_kernel<<<bs, 128, 0, stream>>>(s_ent, rel, ent, relemb, condb, a2);

    const int ntiles = (n_ent + BN - 1) / BN;   // 1563
    score_kernel<<<ntiles, 512, 0, stream>>>(ent, condb, a2, out, n_ent);
}